// Round 7
// baseline (3876.712 us; speedup 1.0000x reference)
//
#include <hip/hip_runtime.h>
#include <hip/hip_bf16.h>

#define BB 32
#define SS 2048
#define DD 1024
#define UU 1024
#define MBLK 64
#define AST 40  // A LDS row stride in elems (80 B: 16B-aligned, conflict-free)

typedef short bf16x8 __attribute__((ext_vector_type(8)));
typedef float f32x2 __attribute__((ext_vector_type(2)));
typedef float f32x4 __attribute__((ext_vector_type(4)));
typedef float f32x16 __attribute__((ext_vector_type(16)));
typedef unsigned int u32;

__device__ __forceinline__ unsigned short f2bf(float x) {
    union { float f; unsigned int u; } v; v.f = x;
    unsigned int r = v.u + 0x7fffu + ((v.u >> 16) & 1u);
    return (unsigned short)(r >> 16);
}

__device__ __forceinline__ f32x2 ntload2(const float* p) {
    return __builtin_nontemporal_load(reinterpret_cast<const f32x2*>(p));
}

__device__ __forceinline__ f32x4 ntload4(const float* p) {
    return __builtin_nontemporal_load(reinterpret_cast<const f32x4*>(p));
}

__device__ __forceinline__ u32 cvtpk(float lo, float hi) {
    u32 r;
    asm("v_cvt_pk_bf16_f32 %0, %1, %2" : "=v"(r) : "v"(lo), "v"(hi));
    return r;
}

// ---------------- K1a: q_proj = query@w1 + b1 + b2 ----------------
__global__ void qproj_kernel(const float* __restrict__ query, const float* __restrict__ w1,
                             const float* __restrict__ b1, const float* __restrict__ b2,
                             float* __restrict__ qp2) {
    __shared__ float qs[DD];
    const int b = blockIdx.x;   // 32
    const int uc = blockIdx.y;  // 4
    const int t = threadIdx.x;  // 256
    for (int i = t; i < DD; i += 256) qs[i] = query[b * DD + i];
    __syncthreads();
    const int u = uc * 256 + t;
    float acc = 0.f;
#pragma unroll 4
    for (int d = 0; d < DD; ++d) acc = fmaf(qs[d], w1[d * UU + u], acc);
    qp2[b * UU + u] = acc + b1[u] + b2[u];
}

// ---------------- K1b: w2t[u][d] = bf16(w2[d][u]) ----------------
__global__ void w2t_kernel(const float* __restrict__ w2, unsigned short* __restrict__ w2t) {
    __shared__ float tile[64][65];
    const int u0 = blockIdx.x * 64;
    const int d0 = blockIdx.y * 64;
    const int t = threadIdx.x;
    const int c = t & 63, rg = t >> 6;
#pragma unroll
    for (int rr = 0; rr < 16; ++rr) {
        int dl = rg * 16 + rr;
        tile[dl][c] = w2[(size_t)(d0 + dl) * UU + u0 + c];
    }
    __syncthreads();
#pragma unroll
    for (int rr = 0; rr < 16; ++rr) {
        int ul = rg * 16 + rr;
        w2t[(size_t)(u0 + ul) * DD + d0 + c] = f2bf(tile[c][ul]);
    }
}

// ---------------- K2: fused GEMM + tanh + wv-reduce -> score[b,s] ----------------
// 1024 thr / 16 waves. Each wave: one 64x64 output tile (rows 0..63 x cols wid*64..+64),
// 32x32x16 MFMA (R5-verified layouts), acc[2][2] f32x16.
// K-loop BK=32, 2-phase: A (values f32->bf16) double-buffered in LDS [64][40];
// next-step A-load + this-step B-frag loads issued FIRST, one barrier per step.
__global__ __launch_bounds__(1024, 8)
void score_kernel(const float* __restrict__ values, const unsigned short* __restrict__ w2t,
                  const float* __restrict__ qp2, const float* __restrict__ wv,
                  const float* __restrict__ bv, float* __restrict__ score) {
    __shared__ __align__(16) unsigned short As[2][MBLK * AST];  // 2 x 5 KB
    __shared__ float ssum[16][MBLK];                             // 4 KB

    const int blk = blockIdx.x;       // 1024
    const int b = blk >> 5;
    const int s0 = (blk & 31) * MBLK;
    const int tid = threadIdx.x;
    const int lane = tid & 63;
    const int wid = tid >> 6;          // 0..15
    const int col = lane & 31;         // A row / B col / D col
    const int h8 = (lane >> 5) * 8;    // k-offset within frag
    const int nb = wid * 64;           // this wave's 64-col U-slice

    // staging: 1024 thr cover 64 rows x 32 k as f32x2 each
    const int srow = tid >> 4;         // 0..63
    const int sk2 = (tid & 15) * 2;    // 0..30
    const float* abase = values + ((size_t)b * SS + s0 + srow) * DD + sk2;
    const int awidx = srow * (AST / 2) + (tid & 15);  // u32 slot

    f32x16 acc[2][2];
#pragma unroll
    for (int mg = 0; mg < 2; ++mg)
#pragma unroll
        for (int ng = 0; ng < 2; ++ng)
#pragma unroll
            for (int r = 0; r < 16; ++r) acc[mg][ng][r] = 0.f;

    // prologue: stage K-tile 0
    {
        f32x2 v = ntload2(abase);
        reinterpret_cast<u32*>(As[0])[awidx] = cvtpk(v[0], v[1]);
    }
    __syncthreads();

#pragma unroll 2
    for (int t = 0; t < 32; ++t) {
        const int cur = t & 1;
        // 1) issue next A-tile global load (in flight across whole step)
        f32x2 av;
        if (t < 31) av = ntload2(abase + (t + 1) * 32);
        // 2) issue this step's B-frag loads (L2-resident w2t)
        bf16x8 bF[2][2];
#pragma unroll
        for (int ng = 0; ng < 2; ++ng)
#pragma unroll
            for (int kk = 0; kk < 2; ++kk)
                bF[ng][kk] = *reinterpret_cast<const bf16x8*>(
                    w2t + (size_t)(nb + ng * 32 + col) * DD + t * 32 + kk * 16 + h8);
        // 3) A frags from LDS
        bf16x8 aF[2][2];
#pragma unroll
        for (int mg = 0; mg < 2; ++mg)
#pragma unroll
            for (int kk = 0; kk < 2; ++kk)
                aF[mg][kk] = *reinterpret_cast<const bf16x8*>(
                    &As[cur][(mg * 32 + col) * AST + kk * 16 + h8]);
        // 4) MFMA
#pragma unroll
        for (int kk = 0; kk < 2; ++kk)
#pragma unroll
            for (int mg = 0; mg < 2; ++mg)
#pragma unroll
                for (int ng = 0; ng < 2; ++ng)
                    acc[mg][ng] = __builtin_amdgcn_mfma_f32_32x32x16_bf16(
                        aF[mg][kk], bF[ng][kk], acc[mg][ng], 0, 0, 0);
        // 5) convert + write next A-tile, 6) one barrier per step
        if (t < 31)
            reinterpret_cast<u32*>(As[cur ^ 1])[awidx] = cvtpk(av[0], av[1]);
        __syncthreads();
    }

    // epilogue: tanh + wv weighting (R5-verified C/D layout)
    float rs[2][16];
#pragma unroll
    for (int mg = 0; mg < 2; ++mg)
#pragma unroll
        for (int r = 0; r < 16; ++r) rs[mg][r] = 0.f;
#pragma unroll
    for (int ng = 0; ng < 2; ++ng) {
        const int u = nb + ng * 32 + col;
        const float qv = qp2[b * UU + u];
        const float wvv = wv[u];
#pragma unroll
        for (int mg = 0; mg < 2; ++mg)
#pragma unroll
            for (int r = 0; r < 16; ++r) {
                float h = acc[mg][ng][r] + qv;
                float e = __expf(2.f * h);
                float th = 1.f - 2.f / (e + 1.f);
                rs[mg][r] = fmaf(th, wvv, rs[mg][r]);
            }
    }
    // reduce across 32 cols (independent per 32-lane half)
#pragma unroll
    for (int mg = 0; mg < 2; ++mg)
#pragma unroll
        for (int r = 0; r < 16; ++r) {
            float v = rs[mg][r];
            v += __shfl_xor(v, 1);
            v += __shfl_xor(v, 2);
            v += __shfl_xor(v, 4);
            v += __shfl_xor(v, 8);
            v += __shfl_xor(v, 16);
            rs[mg][r] = v;
        }
    if ((lane & 31) == 0) {
        const int hi = lane >> 5;
#pragma unroll
        for (int mg = 0; mg < 2; ++mg)
#pragma unroll
            for (int r = 0; r < 16; ++r) {
                const int row = mg * 32 + (r & 3) + 8 * (r >> 2) + 4 * hi;
                ssum[wid][row] = rs[mg][r];
            }
    }
    __syncthreads();
    if (tid < MBLK) {
        float sc = bv[0];
#pragma unroll
        for (int w = 0; w < 16; ++w) sc += ssum[w][tid];
        score[b * SS + s0 + tid] = sc;
    }
}

// ---------------- K3a: softmax over S per batch ----------------
__global__ void softmax_kernel(const float* __restrict__ score, float* __restrict__ weights) {
    __shared__ float red[8];
    const int b = blockIdx.x;
    const int t = threadIdx.x;  // 256
    float local[8];
    float mx = -1e30f;
#pragma unroll
    for (int i = 0; i < 8; ++i) {
        local[i] = score[b * SS + i * 256 + t];
        mx = fmaxf(mx, local[i]);
    }
    for (int off = 1; off < 64; off <<= 1) mx = fmaxf(mx, __shfl_xor(mx, off));
    if ((t & 63) == 0) red[t >> 6] = mx;
    __syncthreads();
    const float m = fmaxf(fmaxf(red[0], red[1]), fmaxf(red[2], red[3]));
    float sum = 0.f;
#pragma unroll
    for (int i = 0; i < 8; ++i) {
        local[i] = __expf(local[i] - m);
        sum += local[i];
    }
    for (int off = 1; off < 64; off <<= 1) sum += __shfl_xor(sum, off);
    if ((t & 63) == 0) red[4 + (t >> 6)] = sum;
    __syncthreads();
    const float inv = 1.f / (red[4] + red[5] + red[6] + red[7]);
#pragma unroll
    for (int i = 0; i < 8; ++i) weights[b * SS + i * 256 + t] = local[i] * inv;
}

// ---------------- K3b: context[b,d] = sum_s w[b,s] * values[b,s,d] ----------------
// grid (32, 32): 32-col chunks, 4 blocks/CU, weights in LDS, deep-unrolled nt loads.
__global__ void context_kernel(const float* __restrict__ values, const float* __restrict__ weights,
                               float* __restrict__ ctx) {
    __shared__ float ws[SS];          // 8 KB
    __shared__ f32x4 red[32][8];      // 4 KB
    const int b = blockIdx.x;   // 32
    const int dc = blockIdx.y;  // 32
    const int t = threadIdx.x;  // 256
    for (int i = t; i < SS; i += 256) ws[i] = weights[b * SS + i];
    __syncthreads();
    const int dt = t & 7;       // 8 d-threads (32 cols)
    const int ph = t >> 3;      // 32 s-phases
    const int d = dc * 32 + dt * 4;
    const float* vb = values + (size_t)b * SS * DD + d;
    f32x4 acc = {0.f, 0.f, 0.f, 0.f};
#pragma unroll 8
    for (int s = ph; s < SS; s += 32) {
        const float w = ws[s];
        f32x4 v = ntload4(vb + (size_t)s * DD);
        acc[0] = fmaf(w, v[0], acc[0]);
        acc[1] = fmaf(w, v[1], acc[1]);
        acc[2] = fmaf(w, v[2], acc[2]);
        acc[3] = fmaf(w, v[3], acc[3]);
    }
    red[ph][dt] = acc;
    __syncthreads();
    if (t < 8) {
        f32x4 r = red[0][t];
#pragma unroll
        for (int w = 1; w < 32; ++w) {
            f32x4 x = red[w][t];
#pragma unroll
            for (int i = 0; i < 4; ++i) r[i] += x[i];
        }
        *reinterpret_cast<f32x4*>(ctx + (size_t)b * DD + dc * 32 + t * 4) = r;
    }
}

extern "C" void kernel_launch(void* const* d_in, const int* in_sizes, int n_in,
                              void* d_out, int out_size, void* d_ws, size_t ws_size,
                              hipStream_t stream) {
    const float* query  = (const float*)d_in[0];
    const float* values = (const float*)d_in[1];
    const float* w1     = (const float*)d_in[2];
    const float* b1     = (const float*)d_in[3];
    const float* w2     = (const float*)d_in[4];
    const float* b2     = (const float*)d_in[5];
    const float* wv     = (const float*)d_in[6];
    const float* bv     = (const float*)d_in[7];

    float* ctx     = (float*)d_out;                    // [B, D]
    float* weights = (float*)d_out + (size_t)BB * DD;  // [B, S, 1]

    float* qp2           = (float*)d_ws;                                  // 128 KB
    unsigned short* w2t  = (unsigned short*)((char*)d_ws + 131072);       // 2 MB
    float* score         = (float*)((char*)d_ws + 131072 + 2097152);      // 256 KB

    qproj_kernel<<<dim3(BB, UU / 256), 256, 0, stream>>>(query, w1, b1, b2, qp2);
    w2t_kernel<<<dim3(UU / 64, DD / 64), 256, 0, stream>>>(w2, w2t);
    score_kernel<<<dim3(BB * SS / MBLK), 1024, 0, stream>>>(values, w2t, qp2, wv, bv, score);
    softmax_kernel<<<dim3(BB), 256, 0, stream>>>(score, weights);
    context_kernel<<<dim3(BB, 32), 256, 0, stream>>>(values, weights, ctx);
}

// Round 8
// 577.379 us; speedup vs baseline: 6.7143x; 6.7143x over previous
//
#include <hip/hip_runtime.h>
#include <hip/hip_bf16.h>

#define BB 32
#define SS 2048
#define DD 1024
#define UU 1024
#define MBLK 64
#define AST 40  // A LDS row stride in elems (80 B: 16B-aligned, conflict-free)

typedef short bf16x8 __attribute__((ext_vector_type(8)));
typedef float f32x2 __attribute__((ext_vector_type(2)));
typedef float f32x4 __attribute__((ext_vector_type(4)));
typedef float f32x16 __attribute__((ext_vector_type(16)));
typedef unsigned int u32;

__device__ __forceinline__ unsigned short f2bf(float x) {
    union { float f; unsigned int u; } v; v.f = x;
    unsigned int r = v.u + 0x7fffu + ((v.u >> 16) & 1u);
    return (unsigned short)(r >> 16);
}

__device__ __forceinline__ f32x2 ntload2(const float* p) {
    return __builtin_nontemporal_load(reinterpret_cast<const f32x2*>(p));
}

__device__ __forceinline__ f32x4 ntload4(const float* p) {
    return __builtin_nontemporal_load(reinterpret_cast<const f32x4*>(p));
}

__device__ __forceinline__ u32 cvtpk(float lo, float hi) {
    u32 r;
    asm("v_cvt_pk_bf16_f32 %0, %1, %2" : "=v"(r) : "v"(lo), "v"(hi));
    return r;
}

// ---------------- K1a: q_proj = query@w1 + b1 + b2 ----------------
__global__ void qproj_kernel(const float* __restrict__ query, const float* __restrict__ w1,
                             const float* __restrict__ b1, const float* __restrict__ b2,
                             float* __restrict__ qp2) {
    __shared__ float qs[DD];
    const int b = blockIdx.x;   // 32
    const int uc = blockIdx.y;  // 4
    const int t = threadIdx.x;  // 256
    for (int i = t; i < DD; i += 256) qs[i] = query[b * DD + i];
    __syncthreads();
    const int u = uc * 256 + t;
    float acc = 0.f;
#pragma unroll 4
    for (int d = 0; d < DD; ++d) acc = fmaf(qs[d], w1[d * UU + u], acc);
    qp2[b * UU + u] = acc + b1[u] + b2[u];
}

// ---------------- K1b: w2t[u][d] = bf16(w2[d][u]) ----------------
__global__ void w2t_kernel(const float* __restrict__ w2, unsigned short* __restrict__ w2t) {
    __shared__ float tile[64][65];
    const int u0 = blockIdx.x * 64;
    const int d0 = blockIdx.y * 64;
    const int t = threadIdx.x;
    const int c = t & 63, rg = t >> 6;
#pragma unroll
    for (int rr = 0; rr < 16; ++rr) {
        int dl = rg * 16 + rr;
        tile[dl][c] = w2[(size_t)(d0 + dl) * UU + u0 + c];
    }
    __syncthreads();
#pragma unroll
    for (int rr = 0; rr < 16; ++rr) {
        int ul = rg * 16 + rr;
        w2t[(size_t)(u0 + ul) * DD + d0 + c] = f2bf(tile[c][ul]);
    }
}

// ---------------- K2: fused GEMM + tanh + wv-reduce -> score[b,s] ----------------
// 1024 thr / 16 waves. Each wave: one 64x64 output tile, 32x32x16 MFMA,
// acc[2][2] f32x16 (64 VGPR). K-loop BK=32, 2-phase double-buffered A in LDS [64][40];
// next-step A-load + this-step B-frags issued FIRST, one barrier per step.
// launch_bounds(1024, 2): 2 waves/SIMD min -> 256-VGPR budget (R7's (1024,8) forced
// a 64-VGPR cap and spilled acc to scratch).
__global__ __launch_bounds__(1024, 2)
void score_kernel(const float* __restrict__ values, const unsigned short* __restrict__ w2t,
                  const float* __restrict__ qp2, const float* __restrict__ wv,
                  const float* __restrict__ bv, float* __restrict__ score) {
    __shared__ __align__(16) unsigned short As[2][MBLK * AST];  // 2 x 5 KB
    __shared__ float ssum[16][MBLK];                             // 4 KB

    const int blk = blockIdx.x;       // 1024
    const int b = blk >> 5;
    const int s0 = (blk & 31) * MBLK;
    const int tid = threadIdx.x;
    const int lane = tid & 63;
    const int wid = tid >> 6;          // 0..15
    const int col = lane & 31;         // A row / B col / D col
    const int h8 = (lane >> 5) * 8;    // k-offset within frag
    const int nb = wid * 64;           // this wave's 64-col U-slice

    // staging: 1024 thr cover 64 rows x 32 k as f32x2 each
    const int srow = tid >> 4;         // 0..63
    const int sk2 = (tid & 15) * 2;    // 0..30
    const float* abase = values + ((size_t)b * SS + s0 + srow) * DD + sk2;
    const int awidx = srow * (AST / 2) + (tid & 15);  // u32 slot

    f32x16 acc[2][2];
#pragma unroll
    for (int mg = 0; mg < 2; ++mg)
#pragma unroll
        for (int ng = 0; ng < 2; ++ng)
#pragma unroll
            for (int r = 0; r < 16; ++r) acc[mg][ng][r] = 0.f;

    // prologue: stage K-tile 0
    {
        f32x2 v = ntload2(abase);
        reinterpret_cast<u32*>(As[0])[awidx] = cvtpk(v[0], v[1]);
    }
    __syncthreads();

#pragma unroll 2
    for (int t = 0; t < 32; ++t) {
        const int cur = t & 1;
        // 1) issue next A-tile global load (in flight across whole step)
        f32x2 av;
        if (t < 31) av = ntload2(abase + (t + 1) * 32);
        // 2) issue this step's B-frag loads (L2-resident w2t)
        bf16x8 bF[2][2];
#pragma unroll
        for (int ng = 0; ng < 2; ++ng)
#pragma unroll
            for (int kk = 0; kk < 2; ++kk)
                bF[ng][kk] = *reinterpret_cast<const bf16x8*>(
                    w2t + (size_t)(nb + ng * 32 + col) * DD + t * 32 + kk * 16 + h8);
        // 3) A frags from LDS
        bf16x8 aF[2][2];
#pragma unroll
        for (int mg = 0; mg < 2; ++mg)
#pragma unroll
            for (int kk = 0; kk < 2; ++kk)
                aF[mg][kk] = *reinterpret_cast<const bf16x8*>(
                    &As[cur][(mg * 32 + col) * AST + kk * 16 + h8]);
        // 4) MFMA
#pragma unroll
        for (int kk = 0; kk < 2; ++kk)
#pragma unroll
            for (int mg = 0; mg < 2; ++mg)
#pragma unroll
                for (int ng = 0; ng < 2; ++ng)
                    acc[mg][ng] = __builtin_amdgcn_mfma_f32_32x32x16_bf16(
                        aF[mg][kk], bF[ng][kk], acc[mg][ng], 0, 0, 0);
        // 5) convert + write next A-tile, 6) one barrier per step
        if (t < 31)
            reinterpret_cast<u32*>(As[cur ^ 1])[awidx] = cvtpk(av[0], av[1]);
        __syncthreads();
    }

    // epilogue: tanh + wv weighting (R5-verified C/D layout)
    float rs[2][16];
#pragma unroll
    for (int mg = 0; mg < 2; ++mg)
#pragma unroll
        for (int r = 0; r < 16; ++r) rs[mg][r] = 0.f;
#pragma unroll
    for (int ng = 0; ng < 2; ++ng) {
        const int u = nb + ng * 32 + col;
        const float qv = qp2[b * UU + u];
        const float wvv = wv[u];
#pragma unroll
        for (int mg = 0; mg < 2; ++mg)
#pragma unroll
            for (int r = 0; r < 16; ++r) {
                float h = acc[mg][ng][r] + qv;
                float e = __expf(2.f * h);
                float th = 1.f - 2.f / (e + 1.f);
                rs[mg][r] = fmaf(th, wvv, rs[mg][r]);
            }
    }
    // reduce across 32 cols (independent per 32-lane half)
#pragma unroll
    for (int mg = 0; mg < 2; ++mg)
#pragma unroll
        for (int r = 0; r < 16; ++r) {
            float v = rs[mg][r];
            v += __shfl_xor(v, 1);
            v += __shfl_xor(v, 2);
            v += __shfl_xor(v, 4);
            v += __shfl_xor(v, 8);
            v += __shfl_xor(v, 16);
            rs[mg][r] = v;
        }
    if ((lane & 31) == 0) {
        const int hi = lane >> 5;
#pragma unroll
        for (int mg = 0; mg < 2; ++mg)
#pragma unroll
            for (int r = 0; r < 16; ++r) {
                const int row = mg * 32 + (r & 3) + 8 * (r >> 2) + 4 * hi;
                ssum[wid][row] = rs[mg][r];
            }
    }
    __syncthreads();
    if (tid < MBLK) {
        float sc = bv[0];
#pragma unroll
        for (int w = 0; w < 16; ++w) sc += ssum[w][tid];
        score[b * SS + s0 + tid] = sc;
    }
}

// ---------------- K3a: softmax over S per batch ----------------
__global__ void softmax_kernel(const float* __restrict__ score, float* __restrict__ weights) {
    __shared__ float red[8];
    const int b = blockIdx.x;
    const int t = threadIdx.x;  // 256
    float local[8];
    float mx = -1e30f;
#pragma unroll
    for (int i = 0; i < 8; ++i) {
        local[i] = score[b * SS + i * 256 + t];
        mx = fmaxf(mx, local[i]);
    }
    for (int off = 1; off < 64; off <<= 1) mx = fmaxf(mx, __shfl_xor(mx, off));
    if ((t & 63) == 0) red[t >> 6] = mx;
    __syncthreads();
    const float m = fmaxf(fmaxf(red[0], red[1]), fmaxf(red[2], red[3]));
    float sum = 0.f;
#pragma unroll
    for (int i = 0; i < 8; ++i) {
        local[i] = __expf(local[i] - m);
        sum += local[i];
    }
    for (int off = 1; off < 64; off <<= 1) sum += __shfl_xor(sum, off);
    if ((t & 63) == 0) red[4 + (t >> 6)] = sum;
    __syncthreads();
    const float inv = 1.f / (red[4] + red[5] + red[6] + red[7]);
#pragma unroll
    for (int i = 0; i < 8; ++i) weights[b * SS + i * 256 + t] = local[i] * inv;
}

// ---------------- K3b: context[b,d] = sum_s w[b,s] * values[b,s,d] ----------------
// grid (32, 32): 32-col chunks, 4 blocks/CU, weights in LDS, deep-unrolled nt loads.
__global__ void context_kernel(const float* __restrict__ values, const float* __restrict__ weights,
                               float* __restrict__ ctx) {
    __shared__ float ws[SS];          // 8 KB
    __shared__ f32x4 red[32][8];      // 4 KB
    const int b = blockIdx.x;   // 32
    const int dc = blockIdx.y;  // 32
    const int t = threadIdx.x;  // 256
    for (int i = t; i < SS; i += 256) ws[i] = weights[b * SS + i];
    __syncthreads();
    const int dt = t & 7;       // 8 d-threads (32 cols)
    const int ph = t >> 3;      // 32 s-phases
    const int d = dc * 32 + dt * 4;
    const float* vb = values + (size_t)b * SS * DD + d;
    f32x4 acc = {0.f, 0.f, 0.f, 0.f};
#pragma unroll 8
    for (int s = ph; s < SS; s += 32) {
        const float w = ws[s];
        f32x4 v = ntload4(vb + (size_t)s * DD);
        acc[0] = fmaf(w, v[0], acc[0]);
        acc[1] = fmaf(w, v[1], acc[1]);
        acc[2] = fmaf(w, v[2], acc[2]);
        acc[3] = fmaf(w, v[3], acc[3]);
    }
    red[ph][dt] = acc;
    __syncthreads();
    if (t < 8) {
        f32x4 r = red[0][t];
#pragma unroll
        for (int w = 1; w < 32; ++w) {
            f32x4 x = red[w][t];
#pragma unroll
            for (int i = 0; i < 4; ++i) r[i] += x[i];
        }
        *reinterpret_cast<f32x4*>(ctx + (size_t)b * DD + dc * 32 + t * 4) = r;
    }
}

extern "C" void kernel_launch(void* const* d_in, const int* in_sizes, int n_in,
                              void* d_out, int out_size, void* d_ws, size_t ws_size,
                              hipStream_t stream) {
    const float* query  = (const float*)d_in[0];
    const float* values = (const float*)d_in[1];
    const float* w1     = (const float*)d_in[2];
    const float* b1     = (const float*)d_in[3];
    const float* w2     = (const float*)d_in[4];
    const float* b2     = (const float*)d_in[5];
    const float* wv     = (const float*)d_in[6];
    const float* bv     = (const float*)d_in[7];

    float* ctx     = (float*)d_out;                    // [B, D]
    float* weights = (float*)d_out + (size_t)BB * DD;  // [B, S, 1]

    float* qp2           = (float*)d_ws;                                  // 128 KB
    unsigned short* w2t  = (unsigned short*)((char*)d_ws + 131072);       // 2 MB
    float* score         = (float*)((char*)d_ws + 131072 + 2097152);      // 256 KB

    qproj_kernel<<<dim3(BB, UU / 256), 256, 0, stream>>>(query, w1, b1, b2, qp2);
    w2t_kernel<<<dim3(UU / 64, DD / 64), 256, 0, stream>>>(w2, w2t);
    score_kernel<<<dim3(BB * SS / MBLK), 1024, 0, stream>>>(values, w2t, qp2, wv, bv, score);
    softmax_kernel<<<dim3(BB), 256, 0, stream>>>(score, weights);
    context_kernel<<<dim3(BB, 32), 256, 0, stream>>>(values, weights, ctx);
}

// Round 9
// 415.119 us; speedup vs baseline: 9.3388x; 1.3909x over previous
//
#include <hip/hip_runtime.h>
#include <hip/hip_bf16.h>

#define BB 32
#define SS 2048
#define DD 1024
#define UU 1024
#define MBLK 64
#define AST 40  // A LDS row stride in elems (80 B)

typedef short bf16x8 __attribute__((ext_vector_type(8)));
typedef float f32x4 __attribute__((ext_vector_type(4)));
typedef float f32x16 __attribute__((ext_vector_type(16)));
typedef unsigned int u32;

__device__ __forceinline__ unsigned short f2bf(float x) {
    union { float f; unsigned int u; } v; v.f = x;
    unsigned int r = v.u + 0x7fffu + ((v.u >> 16) & 1u);
    return (unsigned short)(r >> 16);
}

__device__ __forceinline__ f32x4 ntload4(const float* p) {
    return __builtin_nontemporal_load(reinterpret_cast<const f32x4*>(p));
}

__device__ __forceinline__ u32 cvtpk(float lo, float hi) {
    u32 r;
    asm("v_cvt_pk_bf16_f32 %0, %1, %2" : "=v"(r) : "v"(lo), "v"(hi));
    return r;
}

// ---------------- K1a: q_proj = query@w1 + b1 + b2 ----------------
__global__ void qproj_kernel(const float* __restrict__ query, const float* __restrict__ w1,
                             const float* __restrict__ b1, const float* __restrict__ b2,
                             float* __restrict__ qp2) {
    __shared__ float qs[DD];
    const int b = blockIdx.x;   // 32
    const int uc = blockIdx.y;  // 4
    const int t = threadIdx.x;  // 256
    for (int i = t; i < DD; i += 256) qs[i] = query[b * DD + i];
    __syncthreads();
    const int u = uc * 256 + t;
    float acc = 0.f;
#pragma unroll 4
    for (int d = 0; d < DD; ++d) acc = fmaf(qs[d], w1[d * UU + u], acc);
    qp2[b * UU + u] = acc + b1[u] + b2[u];
}

// ---------------- K1b: fragment-packed B: w2p[ub][ks][lane][8] ----------------
// lane l of a wave reads w2p contiguously; contents: col = ub*32 + (l&31),
// k = ks*16 + (l>>5)*8 + e  (exactly the 32x32x16 B-frag layout verified in R5-R8).
__global__ void w2p_kernel(const float* __restrict__ w2, unsigned short* __restrict__ w2p) {
    const int tid = blockIdx.x * 256 + threadIdx.x;  // 0..131071
    const int lane = tid & 63;
    const int pair = tid >> 6;     // 0..2047 = ub*64 + ks
    const int ks = pair & 63;
    const int ub = pair >> 6;
    const int colg = ub * 32 + (lane & 31);
    const int k0 = ks * 16 + (lane >> 5) * 8;
    bf16x8 pk;
#pragma unroll
    for (int e = 0; e < 8; ++e) pk[e] = (short)f2bf(w2[(size_t)(k0 + e) * UU + colg]);
    *reinterpret_cast<bf16x8*>(&w2p[(size_t)tid * 8]) = pk;
}

// ---------------- K2: fused GEMM + tanh + wv-reduce -> score[b,s] ----------------
// 512 thr / 8 waves, 2 blocks/CU (launch_bounds(512,2) -> 256-reg budget).
// Each wave: 64 rows x 64 cols x 2 U-halves; acc[2][2][2] f32x16 = 128 AGPR.
// K-loop BK=32, double-buffered A in LDS; B via fragment-packed w2p (coalesced 1KB loads).
__global__ __launch_bounds__(512, 2)
void score_kernel(const float* __restrict__ values, const unsigned short* __restrict__ w2p,
                  const float* __restrict__ qp2, const float* __restrict__ wv,
                  const float* __restrict__ bv, float* __restrict__ score) {
    __shared__ __align__(16) unsigned short As[2][MBLK * AST];  // 2 x 5 KB
    __shared__ float ssum[8][MBLK];                              // 2 KB

    const int blk = blockIdx.x;       // 1024
    const int b = blk >> 5;
    const int s0 = (blk & 31) * MBLK;
    const int tid = threadIdx.x;
    const int lane = tid & 63;
    const int wid = tid >> 6;          // 0..7
    const int col = lane & 31;
    const int h8 = (lane >> 5) * 8;

    // staging: 64 rows x 8 thr/row x 4 f32
    const int srow = tid >> 3;
    const int sc4 = (tid & 7) * 4;
    const float* abase = values + ((size_t)b * SS + s0 + srow) * DD + sc4;
    const int awidx = srow * (AST / 2) + (tid & 7) * 2;  // u32 slot

    const unsigned short* wpb = w2p + (size_t)lane * 8;

    f32x16 acc[2][2][2];  // [pass][mg][ng]
#pragma unroll
    for (int ps = 0; ps < 2; ++ps)
#pragma unroll
        for (int mg = 0; mg < 2; ++mg)
#pragma unroll
            for (int ng = 0; ng < 2; ++ng)
#pragma unroll
                for (int r = 0; r < 16; ++r) acc[ps][mg][ng][r] = 0.f;

    // prologue: stage K-tile 0
    {
        f32x4 v = ntload4(abase);
        u32* d = reinterpret_cast<u32*>(As[0]);
        d[awidx] = cvtpk(v[0], v[1]);
        d[awidx + 1] = cvtpk(v[2], v[3]);
    }
    __syncthreads();

#pragma unroll 2
    for (int t = 0; t < 32; ++t) {
        const int cur = t & 1;
        // 1) next A-tile global load in flight across the step
        f32x4 av;
        if (t < 31) av = ntload4(abase + (t + 1) * 32);
        // 2) B-frags: contiguous 1KB coalesced loads from packed w2p
        bf16x8 bF[2][2][2];  // [pass][ng][kk]
#pragma unroll
        for (int ps = 0; ps < 2; ++ps)
#pragma unroll
            for (int ng = 0; ng < 2; ++ng)
#pragma unroll
                for (int kk = 0; kk < 2; ++kk)
                    bF[ps][ng][kk] = *reinterpret_cast<const bf16x8*>(
                        wpb + ((size_t)((ps * 16 + wid * 2 + ng) * 64 + (t * 2 + kk)) << 9));
        // 3) A-frags from LDS
        bf16x8 aF[2][2];
#pragma unroll
        for (int mg = 0; mg < 2; ++mg)
#pragma unroll
            for (int kk = 0; kk < 2; ++kk)
                aF[mg][kk] = *reinterpret_cast<const bf16x8*>(
                    &As[cur][(mg * 32 + col) * AST + kk * 16 + h8]);
        // 4) 16 MFMA
#pragma unroll
        for (int kk = 0; kk < 2; ++kk)
#pragma unroll
            for (int ps = 0; ps < 2; ++ps)
#pragma unroll
                for (int mg = 0; mg < 2; ++mg)
#pragma unroll
                    for (int ng = 0; ng < 2; ++ng)
                        acc[ps][mg][ng] = __builtin_amdgcn_mfma_f32_32x32x16_bf16(
                            aF[mg][kk], bF[ps][ng][kk], acc[ps][mg][ng], 0, 0, 0);
        // 5) convert + write next A-tile, 6) one barrier per step
        if (t < 31) {
            u32* d = reinterpret_cast<u32*>(As[cur ^ 1]);
            d[awidx] = cvtpk(av[0], av[1]);
            d[awidx + 1] = cvtpk(av[2], av[3]);
        }
        __syncthreads();
    }

    // epilogue: tanh + wv weighting
    float rs[2][16];
#pragma unroll
    for (int mg = 0; mg < 2; ++mg)
#pragma unroll
        for (int r = 0; r < 16; ++r) rs[mg][r] = 0.f;
#pragma unroll
    for (int ps = 0; ps < 2; ++ps)
#pragma unroll
        for (int ng = 0; ng < 2; ++ng) {
            const int u = ps * 512 + wid * 64 + ng * 32 + col;
            const float qv = qp2[b * UU + u];
            const float wvv = wv[u];
#pragma unroll
            for (int mg = 0; mg < 2; ++mg)
#pragma unroll
                for (int r = 0; r < 16; ++r) {
                    float h = acc[ps][mg][ng][r] + qv;
                    float e = __expf(2.f * h);
                    float th = 1.f - 2.f / (e + 1.f);
                    rs[mg][r] = fmaf(th, wvv, rs[mg][r]);
                }
        }
    // reduce across 32 cols (independent per 32-lane half)
#pragma unroll
    for (int mg = 0; mg < 2; ++mg)
#pragma unroll
        for (int r = 0; r < 16; ++r) {
            float v = rs[mg][r];
            v += __shfl_xor(v, 1);
            v += __shfl_xor(v, 2);
            v += __shfl_xor(v, 4);
            v += __shfl_xor(v, 8);
            v += __shfl_xor(v, 16);
            rs[mg][r] = v;
        }
    if ((lane & 31) == 0) {
        const int hi = lane >> 5;
#pragma unroll
        for (int mg = 0; mg < 2; ++mg)
#pragma unroll
            for (int r = 0; r < 16; ++r) {
                const int row = mg * 32 + (r & 3) + 8 * (r >> 2) + 4 * hi;
                ssum[wid][row] = rs[mg][r];
            }
    }
    __syncthreads();
    if (tid < MBLK) {
        float sc = bv[0];
#pragma unroll
        for (int w = 0; w < 8; ++w) sc += ssum[w][tid];
        score[b * SS + s0 + tid] = sc;
    }
}

// ---------------- K3a: softmax over S per batch ----------------
__global__ void softmax_kernel(const float* __restrict__ score, float* __restrict__ weights) {
    __shared__ float red[8];
    const int b = blockIdx.x;
    const int t = threadIdx.x;  // 256
    float local[8];
    float mx = -1e30f;
#pragma unroll
    for (int i = 0; i < 8; ++i) {
        local[i] = score[b * SS + i * 256 + t];
        mx = fmaxf(mx, local[i]);
    }
    for (int off = 1; off < 64; off <<= 1) mx = fmaxf(mx, __shfl_xor(mx, off));
    if ((t & 63) == 0) red[t >> 6] = mx;
    __syncthreads();
    const float m = fmaxf(fmaxf(red[0], red[1]), fmaxf(red[2], red[3]));
    float sum = 0.f;
#pragma unroll
    for (int i = 0; i < 8; ++i) {
        local[i] = __expf(local[i] - m);
        sum += local[i];
    }
    for (int off = 1; off < 64; off <<= 1) sum += __shfl_xor(sum, off);
    if ((t & 63) == 0) red[4 + (t >> 6)] = sum;
    __syncthreads();
    const float inv = 1.f / (red[4] + red[5] + red[6] + red[7]);
#pragma unroll
    for (int i = 0; i < 8; ++i) weights[b * SS + i * 256 + t] = local[i] * inv;
}

// ---------------- K3b: context[b,d] = sum_s w[b,s] * values[b,s,d] ----------------
__global__ void context_kernel(const float* __restrict__ values, const float* __restrict__ weights,
                               float* __restrict__ ctx) {
    __shared__ float ws[SS];          // 8 KB
    __shared__ f32x4 red[16][16];     // 4 KB
    const int b = blockIdx.x;   // 32
    const int dc = blockIdx.y;  // 16
    const int t = threadIdx.x;  // 256
    for (int i = t; i < SS; i += 256) ws[i] = weights[b * SS + i];
    __syncthreads();
    const int dt = t & 15;      // 16 d-threads (64 cols)
    const int ph = t >> 4;      // 16 s-phases
    const int d = dc * 64 + dt * 4;
    const float* vb = values + (size_t)b * SS * DD + d;
    f32x4 acc = {0.f, 0.f, 0.f, 0.f};
#pragma unroll 8
    for (int s = ph; s < SS; s += 16) {
        const float w = ws[s];
        f32x4 v = ntload4(vb + (size_t)s * DD);
        acc[0] = fmaf(w, v[0], acc[0]);
        acc[1] = fmaf(w, v[1], acc[1]);
        acc[2] = fmaf(w, v[2], acc[2]);
        acc[3] = fmaf(w, v[3], acc[3]);
    }
    red[ph][dt] = acc;
    __syncthreads();
    if (t < 16) {
        f32x4 r = red[0][t];
#pragma unroll
        for (int w = 1; w < 16; ++w) {
            f32x4 x = red[w][t];
#pragma unroll
            for (int i = 0; i < 4; ++i) r[i] += x[i];
        }
        *reinterpret_cast<f32x4*>(ctx + (size_t)b * DD + dc * 64 + t * 4) = r;
    }
}

extern "C" void kernel_launch(void* const* d_in, const int* in_sizes, int n_in,
                              void* d_out, int out_size, void* d_ws, size_t ws_size,
                              hipStream_t stream) {
    const float* query  = (const float*)d_in[0];
    const float* values = (const float*)d_in[1];
    const float* w1     = (const float*)d_in[2];
    const float* b1     = (const float*)d_in[3];
    const float* w2     = (const float*)d_in[4];
    const float* b2     = (const float*)d_in[5];
    const float* wv     = (const float*)d_in[6];
    const float* bv     = (const float*)d_in[7];

    float* ctx     = (float*)d_out;                    // [B, D]
    float* weights = (float*)d_out + (size_t)BB * DD;  // [B, S, 1]

    float* qp2           = (float*)d_ws;                                  // 128 KB
    unsigned short* w2p  = (unsigned short*)((char*)d_ws + 131072);       // 2 MB
    float* score         = (float*)((char*)d_ws + 131072 + 2097152);      // 256 KB

    qproj_kernel<<<dim3(BB, UU / 256), 256, 0, stream>>>(query, w1, b1, b2, qp2);
    w2p_kernel<<<dim3(512), 256, 0, stream>>>(w2, w2p);
    score_kernel<<<dim3(BB * SS / MBLK), 512, 0, stream>>>(values, w2p, qp2, wv, bv, score);
    softmax_kernel<<<dim3(BB), 256, 0, stream>>>(score, weights);
    context_kernel<<<dim3(BB, 16), 256, 0, stream>>>(values, weights, ctx);
}

// Round 10
// 354.565 us; speedup vs baseline: 10.9337x; 1.1708x over previous
//
#include <hip/hip_runtime.h>
#include <hip/hip_bf16.h>

#define BB 32
#define SS 2048
#define DD 1024
#define UU 1024
#define MBLK 64
#define AST 80  // A LDS row stride in shorts (160 B, 16B-aligned)

typedef short bf16x8 __attribute__((ext_vector_type(8)));
typedef float f32x4 __attribute__((ext_vector_type(4)));
typedef float f32x16 __attribute__((ext_vector_type(16)));
typedef unsigned int u32;

__device__ __forceinline__ unsigned short f2bf(float x) {
    union { float f; unsigned int u; } v; v.f = x;
    unsigned int r = v.u + 0x7fffu + ((v.u >> 16) & 1u);
    return (unsigned short)(r >> 16);
}

__device__ __forceinline__ f32x4 ntload4(const float* p) {
    return __builtin_nontemporal_load(reinterpret_cast<const f32x4*>(p));
}

__device__ __forceinline__ u32 cvtpk(float lo, float hi) {
    u32 r;
    asm("v_cvt_pk_bf16_f32 %0, %1, %2" : "=v"(r) : "v"(lo), "v"(hi));
    return r;
}

// ---------------- K1a: q_proj = query@w1 + b1 + b2 ----------------
__global__ void qproj_kernel(const float* __restrict__ query, const float* __restrict__ w1,
                             const float* __restrict__ b1, const float* __restrict__ b2,
                             float* __restrict__ qp2) {
    __shared__ float qs[DD];
    const int b = blockIdx.x;   // 32
    const int uc = blockIdx.y;  // 4
    const int t = threadIdx.x;  // 256
    for (int i = t; i < DD; i += 256) qs[i] = query[b * DD + i];
    __syncthreads();
    const int u = uc * 256 + t;
    float acc = 0.f;
#pragma unroll 4
    for (int d = 0; d < DD; ++d) acc = fmaf(qs[d], w1[d * UU + u], acc);
    qp2[b * UU + u] = acc + b1[u] + b2[u];
}

// ---------------- K1b: fragment-packed B: w2p[ub][ks][lane][8] ----------------
__global__ void w2p_kernel(const float* __restrict__ w2, unsigned short* __restrict__ w2p) {
    const int tid = blockIdx.x * 256 + threadIdx.x;  // 0..131071
    const int lane = tid & 63;
    const int pair = tid >> 6;     // ub*64 + ks
    const int ks = pair & 63;
    const int ub = pair >> 6;
    const int colg = ub * 32 + (lane & 31);
    const int k0 = ks * 16 + (lane >> 5) * 8;
    bf16x8 pk;
#pragma unroll
    for (int e = 0; e < 8; ++e) pk[e] = (short)f2bf(w2[(size_t)(k0 + e) * UU + colg]);
    *reinterpret_cast<bf16x8*>(&w2p[(size_t)tid * 8]) = pk;
}

// ---------------- K2: fused GEMM + tanh + wv-reduce -> score[b,s] ----------------
// 512 thr / 8 waves. BK=64, 16 K-steps. Raw s_barrier + lgkmcnt(0) only (vmem queue
// survives the barrier). A: depth-2 register ring (tile t+2 issued late in step t,
// written to LDS at end of step t+1). LDS A: [2][64][80] bf16, k8^(row&7) swizzle.
// B: packed frags from L2, loaded per-ps to bound register pressure.
__global__ __launch_bounds__(512, 2)
void score_kernel(const float* __restrict__ values, const unsigned short* __restrict__ w2p,
                  const float* __restrict__ qp2, const float* __restrict__ wv,
                  const float* __restrict__ bv, float* __restrict__ score) {
    __shared__ __align__(16) unsigned short Asw[2][MBLK * AST];  // 2 x 10 KB
    __shared__ float ssum[8][MBLK];                               // 2 KB

    const int blk = blockIdx.x;       // 1024
    const int b = blk >> 5;
    const int s0 = (blk & 31) * MBLK;
    const int tid = threadIdx.x;
    const int lane = tid & 63;
    const int wid = tid >> 6;          // 0..7
    const int col = lane & 31;
    const int hi = lane >> 5;

    // staging role: thread covers row srow, k8-block sk8 (8 f32 -> 8 bf16 = 1 ds_write_b128)
    const int srow = tid >> 3;         // 0..63
    const int sk8 = tid & 7;           // 0..7
    const float* pA = values + ((size_t)b * SS + s0 + srow) * DD + sk8 * 8;
    const int wpos = srow * AST + (sk8 ^ (srow & 7)) * 8;  // shorts

    const unsigned short* wpb = w2p + (size_t)lane * 8;

    f32x16 acc[2][2][2];  // [ps][mg][ng]
#pragma unroll
    for (int ps = 0; ps < 2; ++ps)
#pragma unroll
        for (int mg = 0; mg < 2; ++mg)
#pragma unroll
            for (int ng = 0; ng < 2; ++ng)
#pragma unroll
                for (int r = 0; r < 16; ++r) acc[ps][mg][ng][r] = 0.f;

    f32x4 avc0, avc1, avn0, avn1;

    // prologue: tile0 -> buf0; tile1 -> regs
    avc0 = ntload4(pA);
    avc1 = ntload4(pA + 4);
    {
        u32 q0 = cvtpk(avc0[0], avc0[1]), q1 = cvtpk(avc0[2], avc0[3]);
        u32 q2 = cvtpk(avc1[0], avc1[1]), q3 = cvtpk(avc1[2], avc1[3]);
        u32* d = reinterpret_cast<u32*>(&Asw[0][wpos]);
        d[0] = q0; d[1] = q1; d[2] = q2; d[3] = q3;
    }
    avc0 = ntload4(pA + 64);
    avc1 = ntload4(pA + 68);
    asm volatile("s_waitcnt lgkmcnt(0)" ::: "memory");
    __builtin_amdgcn_s_barrier();

#pragma unroll 1
    for (int t = 0; t < 16; ++t) {
        const int cur = t & 1;
        // A frags from LDS (swizzled)
        bf16x8 aF[2][4];
#pragma unroll
        for (int mg = 0; mg < 2; ++mg)
#pragma unroll
            for (int kk = 0; kk < 4; ++kk) {
                const int r = mg * 32 + col;
                const int pos = (kk * 2 + hi) ^ (r & 7);
                aF[mg][kk] = *reinterpret_cast<const bf16x8*>(&Asw[cur][r * AST + pos * 8]);
            }
        // compute per ps (B loads batched per-ps to bound live registers)
#pragma unroll
        for (int ps = 0; ps < 2; ++ps) {
            bf16x8 bF[2][4];
#pragma unroll
            for (int ng = 0; ng < 2; ++ng)
#pragma unroll
                for (int kk = 0; kk < 4; ++kk)
                    bF[ng][kk] = *reinterpret_cast<const bf16x8*>(
                        wpb + ((size_t)((ps * 16 + wid * 2 + ng) * 64 + t * 4 + kk) << 9));
#pragma unroll
            for (int kk = 0; kk < 4; ++kk)
#pragma unroll
                for (int mg = 0; mg < 2; ++mg)
#pragma unroll
                    for (int ng = 0; ng < 2; ++ng)
                        acc[ps][mg][ng] = __builtin_amdgcn_mfma_f32_32x32x16_bf16(
                            aF[mg][kk], bF[ps == 0 ? ng : ng][kk], acc[ps][mg][ng], 0, 0, 0);
        }
        // issue tile t+2 LAST (youngest vmem ops -> B-waits never drain them)
        const int tn = (t + 2 < 16) ? (t + 2) : 15;
        avn0 = ntload4(pA + tn * 64);
        avn1 = ntload4(pA + tn * 64 + 4);
        // write tile t+1 (avc, loaded last step) into the other buffer
        if (t < 15) {
            u32 q0 = cvtpk(avc0[0], avc0[1]), q1 = cvtpk(avc0[2], avc0[3]);
            u32 q2 = cvtpk(avc1[0], avc1[1]), q3 = cvtpk(avc1[2], avc1[3]);
            u32* d = reinterpret_cast<u32*>(&Asw[cur ^ 1][wpos]);
            d[0] = q0; d[1] = q1; d[2] = q2; d[3] = q3;
        }
        avc0 = avn0; avc1 = avn1;
        asm volatile("s_waitcnt lgkmcnt(0)" ::: "memory");
        __builtin_amdgcn_s_barrier();
    }

    // epilogue: tanh + wv weighting (R5-verified C/D layout)
    float rs[2][16];
#pragma unroll
    for (int mg = 0; mg < 2; ++mg)
#pragma unroll
        for (int r = 0; r < 16; ++r) rs[mg][r] = 0.f;
#pragma unroll
    for (int ps = 0; ps < 2; ++ps)
#pragma unroll
        for (int ng = 0; ng < 2; ++ng) {
            const int u = ps * 512 + wid * 64 + ng * 32 + col;
            const float qv = qp2[b * UU + u];
            const float wvv = wv[u];
#pragma unroll
            for (int mg = 0; mg < 2; ++mg)
#pragma unroll
                for (int r = 0; r < 16; ++r) {
                    float h = acc[ps][mg][ng][r] + qv;
                    float e = __expf(2.f * h);
                    float th = 1.f - 2.f / (e + 1.f);
                    rs[mg][r] = fmaf(th, wvv, rs[mg][r]);
                }
        }
#pragma unroll
    for (int mg = 0; mg < 2; ++mg)
#pragma unroll
        for (int r = 0; r < 16; ++r) {
            float v = rs[mg][r];
            v += __shfl_xor(v, 1);
            v += __shfl_xor(v, 2);
            v += __shfl_xor(v, 4);
            v += __shfl_xor(v, 8);
            v += __shfl_xor(v, 16);
            rs[mg][r] = v;
        }
    if ((lane & 31) == 0) {
        const int hh = lane >> 5;
#pragma unroll
        for (int mg = 0; mg < 2; ++mg)
#pragma unroll
            for (int r = 0; r < 16; ++r) {
                const int row = mg * 32 + (r & 3) + 8 * (r >> 2) + 4 * hh;
                ssum[wid][row] = rs[mg][r];
            }
    }
    __syncthreads();
    if (tid < MBLK) {
        float sc = bv[0];
#pragma unroll
        for (int w = 0; w < 8; ++w) sc += ssum[w][tid];
        score[b * SS + s0 + tid] = sc;
    }
}

// ---------------- K3a: softmax over S per batch ----------------
__global__ void softmax_kernel(const float* __restrict__ score, float* __restrict__ weights) {
    __shared__ float red[8];
    const int b = blockIdx.x;
    const int t = threadIdx.x;  // 256
    float local[8];
    float mx = -1e30f;
#pragma unroll
    for (int i = 0; i < 8; ++i) {
        local[i] = score[b * SS + i * 256 + t];
        mx = fmaxf(mx, local[i]);
    }
    for (int off = 1; off < 64; off <<= 1) mx = fmaxf(mx, __shfl_xor(mx, off));
    if ((t & 63) == 0) red[t >> 6] = mx;
    __syncthreads();
    const float m = fmaxf(fmaxf(red[0], red[1]), fmaxf(red[2], red[3]));
    float sum = 0.f;
#pragma unroll
    for (int i = 0; i < 8; ++i) {
        local[i] = __expf(local[i] - m);
        sum += local[i];
    }
    for (int off = 1; off < 64; off <<= 1) sum += __shfl_xor(sum, off);
    if ((t & 63) == 0) red[4 + (t >> 6)] = sum;
    __syncthreads();
    const float inv = 1.f / (red[4] + red[5] + red[6] + red[7]);
#pragma unroll
    for (int i = 0; i < 8; ++i) weights[b * SS + i * 256 + t] = local[i] * inv;
}

// ---------------- K3b: context[b,d] = sum_s w[b,s] * values[b,s,d] ----------------
__global__ void context_kernel(const float* __restrict__ values, const float* __restrict__ weights,
                               float* __restrict__ ctx) {
    __shared__ float ws[SS];          // 8 KB
    __shared__ f32x4 red[16][16];     // 4 KB
    const int b = blockIdx.x;   // 32
    const int dc = blockIdx.y;  // 16
    const int t = threadIdx.x;  // 256
    for (int i = t; i < SS; i += 256) ws[i] = weights[b * SS + i];
    __syncthreads();
    const int dt = t & 15;      // 16 d-threads (64 cols)
    const int ph = t >> 4;      // 16 s-phases
    const int d = dc * 64 + dt * 4;
    const float* vb = values + (size_t)b * SS * DD + d;
    f32x4 acc = {0.f, 0.f, 0.f, 0.f};
#pragma unroll 8
    for (int s = ph; s < SS; s += 16) {
        const float w = ws[s];
        f32x4 v = ntload4(vb + (size_t)s * DD);
        acc[0] = fmaf(w, v[0], acc[0]);
        acc[1] = fmaf(w, v[1], acc[1]);
        acc[2] = fmaf(w, v[2], acc[2]);
        acc[3] = fmaf(w, v[3], acc[3]);
    }
    red[ph][dt] = acc;
    __syncthreads();
    if (t < 16) {
        f32x4 r = red[0][t];
#pragma unroll
        for (int w = 1; w < 16; ++w) {
            f32x4 x = red[w][t];
#pragma unroll
            for (int i = 0; i < 4; ++i) r[i] += x[i];
        }
        *reinterpret_cast<f32x4*>(ctx + (size_t)b * DD + dc * 64 + t * 4) = r;
    }
}

extern "C" void kernel_launch(void* const* d_in, const int* in_sizes, int n_in,
                              void* d_out, int out_size, void* d_ws, size_t ws_size,
                              hipStream_t stream) {
    const float* query  = (const float*)d_in[0];
    const float* values = (const float*)d_in[1];
    const float* w1     = (const float*)d_in[2];
    const float* b1     = (const float*)d_in[3];
    const float* w2     = (const float*)d_in[4];
    const float* b2     = (const float*)d_in[5];
    const float* wv     = (const float*)d_in[6];
    const float* bv     = (const float*)d_in[7];

    float* ctx     = (float*)d_out;                    // [B, D]
    float* weights = (float*)d_out + (size_t)BB * DD;  // [B, S, 1]

    float* qp2           = (float*)d_ws;                                  // 128 KB
    unsigned short* w2p  = (unsigned short*)((char*)d_ws + 131072);       // 2 MB
    float* score         = (float*)((char*)d_ws + 131072 + 2097152);      // 256 KB

    qproj_kernel<<<dim3(BB, UU / 256), 256, 0, stream>>>(query, w1, b1, b2, qp2);
    w2p_kernel<<<dim3(512), 256, 0, stream>>>(w2, w2p);
    score_kernel<<<dim3(BB * SS / MBLK), 512, 0, stream>>>(values, w2p, qp2, wv, bv, score);
    softmax_kernel<<<dim3(BB), 256, 0, stream>>>(score, weights);
    context_kernel<<<dim3(BB, 16), 256, 0, stream>>>(values, weights, ctx);
}

// Round 11
// 343.246 us; speedup vs baseline: 11.2943x; 1.0330x over previous
//
#include <hip/hip_runtime.h>
#include <hip/hip_bf16.h>

#define BB 32
#define SS 2048
#define DD 1024
#define UU 1024
#define MBLK 64
#define AST 80  // A LDS row stride in shorts (160 B)

typedef short bf16x8 __attribute__((ext_vector_type(8)));
typedef float f32x4 __attribute__((ext_vector_type(4)));
typedef float f32x16 __attribute__((ext_vector_type(16)));
typedef unsigned int u32;

__device__ __forceinline__ unsigned short f2bf(float x) {
    union { float f; unsigned int u; } v; v.f = x;
    unsigned int r = v.u + 0x7fffu + ((v.u >> 16) & 1u);
    return (unsigned short)(r >> 16);
}

__device__ __forceinline__ f32x4 ntload4(const float* p) {
    return __builtin_nontemporal_load(reinterpret_cast<const f32x4*>(p));
}

__device__ __forceinline__ u32 cvtpk(float lo, float hi) {
    u32 r;
    asm("v_cvt_pk_bf16_f32 %0, %1, %2" : "=v"(r) : "v"(lo), "v"(hi));
    return r;
}

// ---------------- K1a: q_proj = query@w1 + b1 + b2 ----------------
__global__ void qproj_kernel(const float* __restrict__ query, const float* __restrict__ w1,
                             const float* __restrict__ b1, const float* __restrict__ b2,
                             float* __restrict__ qp2) {
    __shared__ float qs[DD];
    const int b = blockIdx.x;   // 32
    const int uc = blockIdx.y;  // 4
    const int t = threadIdx.x;  // 256
    for (int i = t; i < DD; i += 256) qs[i] = query[b * DD + i];
    __syncthreads();
    const int u = uc * 256 + t;
    float acc = 0.f;
#pragma unroll 4
    for (int d = 0; d < DD; ++d) acc = fmaf(qs[d], w1[d * UU + u], acc);
    qp2[b * UU + u] = acc + b1[u] + b2[u];
}

// ---------------- K1b: fragment-packed B: w2p[ub][ks][lane][8] ----------------
__global__ void w2p_kernel(const float* __restrict__ w2, unsigned short* __restrict__ w2p) {
    const int tid = blockIdx.x * 256 + threadIdx.x;  // 0..131071
    const int lane = tid & 63;
    const int pair = tid >> 6;     // ub*64 + ks
    const int ks = pair & 63;
    const int ub = pair >> 6;
    const int colg = ub * 32 + (lane & 31);
    const int k0 = ks * 16 + (lane >> 5) * 8;
    bf16x8 pk;
#pragma unroll
    for (int e = 0; e < 8; ++e) pk[e] = (short)f2bf(w2[(size_t)(k0 + e) * UU + colg]);
    *reinterpret_cast<bf16x8*>(&w2p[(size_t)tid * 8]) = pk;
}

// ---------------- K2: fused GEMM + tanh + wv-reduce -> score[b,s] ----------------
// 512 thr / 8 waves. BK=64, 16 K-steps, raw s_barrier + lgkmcnt(0) (vmem survives).
// A: depth-2 register ring -> LDS [2][64][80] swizzled. B: packed frags from L2,
// software-pipelined by HALF-STEP: bC holds (t,ps0) loaded during t-1's 2nd half
// (in flight across the barrier); bN=(t,ps1) issued before ps0's MFMAs.
__global__ __launch_bounds__(512, 2)
void score_kernel(const float* __restrict__ values, const unsigned short* __restrict__ w2p,
                  const float* __restrict__ qp2, const float* __restrict__ wv,
                  const float* __restrict__ bv, float* __restrict__ score) {
    __shared__ __align__(16) unsigned short Asw[2][MBLK * AST];  // 2 x 10 KB
    __shared__ float ssum[8][MBLK];                               // 2 KB

    const int blk = blockIdx.x;       // 1024
    const int b = blk >> 5;
    const int s0 = (blk & 31) * MBLK;
    const int tid = threadIdx.x;
    const int lane = tid & 63;
    const int wid = tid >> 6;          // 0..7
    const int col = lane & 31;
    const int hi = lane >> 5;

    // staging role: thread (srow, sk8): 8 f32 -> 8 bf16 = 1 ds_write_b128
    const int srow = tid >> 3;         // 0..63
    const int sk8 = tid & 7;           // 0..7
    const float* pA = values + ((size_t)b * SS + s0 + srow) * DD + sk8 * 8;
    const int wpos = srow * AST + (sk8 ^ (srow & 7)) * 8;  // shorts

    const unsigned short* wpb = w2p + (size_t)lane * 8;

#define BADDR(ps, ng, ks) (wpb + ((size_t)(((ps) * 16 + wid * 2 + (ng)) * 64 + (ks)) << 9))

    f32x16 acc[2][2][2];  // [ps][mg][ng]
#pragma unroll
    for (int ps = 0; ps < 2; ++ps)
#pragma unroll
        for (int mg = 0; mg < 2; ++mg)
#pragma unroll
            for (int ng = 0; ng < 2; ++ng)
#pragma unroll
                for (int r = 0; r < 16; ++r) acc[ps][mg][ng][r] = 0.f;

    f32x4 avc0, avc1, avn0, avn1;
    bf16x8 bC[2][4], bN[2][4];

    // prologue: tile0 -> buf0; tile1 -> regs; preload bC = (t=0, ps0)
    avc0 = ntload4(pA);
    avc1 = ntload4(pA + 4);
    {
        u32 q0 = cvtpk(avc0[0], avc0[1]), q1 = cvtpk(avc0[2], avc0[3]);
        u32 q2 = cvtpk(avc1[0], avc1[1]), q3 = cvtpk(avc1[2], avc1[3]);
        u32* d = reinterpret_cast<u32*>(&Asw[0][wpos]);
        d[0] = q0; d[1] = q1; d[2] = q2; d[3] = q3;
    }
    avc0 = ntload4(pA + 64);
    avc1 = ntload4(pA + 68);
#pragma unroll
    for (int ng = 0; ng < 2; ++ng)
#pragma unroll
        for (int kk = 0; kk < 4; ++kk)
            bC[ng][kk] = *reinterpret_cast<const bf16x8*>(BADDR(0, ng, kk));
    asm volatile("s_waitcnt lgkmcnt(0)" ::: "memory");
    __builtin_amdgcn_s_barrier();

#pragma unroll 1
    for (int t = 0; t < 16; ++t) {
        const int cur = t & 1;
        // A frags from LDS (swizzled)
        bf16x8 aF[2][4];
#pragma unroll
        for (int mg = 0; mg < 2; ++mg)
#pragma unroll
            for (int kk = 0; kk < 4; ++kk) {
                const int r = mg * 32 + col;
                const int pos = (kk * 2 + hi) ^ (r & 7);
                aF[mg][kk] = *reinterpret_cast<const bf16x8*>(&Asw[cur][r * AST + pos * 8]);
            }
        // issue bN = (t, ps1) -- consumed after ps0's 16 MFMAs (~400 cyc cover)
#pragma unroll
        for (int ng = 0; ng < 2; ++ng)
#pragma unroll
            for (int kk = 0; kk < 4; ++kk)
                bN[ng][kk] = *reinterpret_cast<const bf16x8*>(BADDR(1, ng, t * 4 + kk));
        // issue next-next A tile (HBM, consumed next step's write phase)
        const int tn = (t + 2 < 16) ? (t + 2) : 15;
        avn0 = ntload4(pA + tn * 64);
        avn1 = ntload4(pA + tn * 64 + 4);
        // MFMA ps0 on bC (loaded during previous step's 2nd half)
#pragma unroll
        for (int kk = 0; kk < 4; ++kk)
#pragma unroll
            for (int mg = 0; mg < 2; ++mg)
#pragma unroll
                for (int ng = 0; ng < 2; ++ng)
                    acc[0][mg][ng] = __builtin_amdgcn_mfma_f32_32x32x16_bf16(
                        aF[mg][kk], bC[ng][kk], acc[0][mg][ng], 0, 0, 0);
        // reload bC = (t+1, ps0) -- in flight across barrier into next step
        if (t < 15) {
#pragma unroll
            for (int ng = 0; ng < 2; ++ng)
#pragma unroll
                for (int kk = 0; kk < 4; ++kk)
                    bC[ng][kk] = *reinterpret_cast<const bf16x8*>(BADDR(0, ng, (t + 1) * 4 + kk));
        }
        // MFMA ps1 on bN
#pragma unroll
        for (int kk = 0; kk < 4; ++kk)
#pragma unroll
            for (int mg = 0; mg < 2; ++mg)
#pragma unroll
                for (int ng = 0; ng < 2; ++ng)
                    acc[1][mg][ng] = __builtin_amdgcn_mfma_f32_32x32x16_bf16(
                        aF[mg][kk], bN[ng][kk], acc[1][mg][ng], 0, 0, 0);
        // write tile t+1 (avc, loaded last step) into the other buffer
        if (t < 15) {
            u32 q0 = cvtpk(avc0[0], avc0[1]), q1 = cvtpk(avc0[2], avc0[3]);
            u32 q2 = cvtpk(avc1[0], avc1[1]), q3 = cvtpk(avc1[2], avc1[3]);
            u32* d = reinterpret_cast<u32*>(&Asw[cur ^ 1][wpos]);
            d[0] = q0; d[1] = q1; d[2] = q2; d[3] = q3;
        }
        avc0 = avn0; avc1 = avn1;
        asm volatile("s_waitcnt lgkmcnt(0)" ::: "memory");
        __builtin_amdgcn_s_barrier();
    }
#undef BADDR

    // epilogue: tanh + wv weighting (R5-verified C/D layout)
    float rs[2][16];
#pragma unroll
    for (int mg = 0; mg < 2; ++mg)
#pragma unroll
        for (int r = 0; r < 16; ++r) rs[mg][r] = 0.f;
#pragma unroll
    for (int ps = 0; ps < 2; ++ps)
#pragma unroll
        for (int ng = 0; ng < 2; ++ng) {
            const int u = ps * 512 + wid * 64 + ng * 32 + col;
            const float qv = qp2[b * UU + u];
            const float wvv = wv[u];
#pragma unroll
            for (int mg = 0; mg < 2; ++mg)
#pragma unroll
                for (int r = 0; r < 16; ++r) {
                    float h = acc[ps][mg][ng][r] + qv;
                    float e = __expf(2.f * h);
                    float th = 1.f - 2.f / (e + 1.f);
                    rs[mg][r] = fmaf(th, wvv, rs[mg][r]);
                }
        }
#pragma unroll
    for (int mg = 0; mg < 2; ++mg)
#pragma unroll
        for (int r = 0; r < 16; ++r) {
            float v = rs[mg][r];
            v += __shfl_xor(v, 1);
            v += __shfl_xor(v, 2);
            v += __shfl_xor(v, 4);
            v += __shfl_xor(v, 8);
            v += __shfl_xor(v, 16);
            rs[mg][r] = v;
        }
    if ((lane & 31) == 0) {
        const int hh = lane >> 5;
#pragma unroll
        for (int mg = 0; mg < 2; ++mg)
#pragma unroll
            for (int r = 0; r < 16; ++r) {
                const int row = mg * 32 + (r & 3) + 8 * (r >> 2) + 4 * hh;
                ssum[wid][row] = rs[mg][r];
            }
    }
    __syncthreads();
    if (tid < MBLK) {
        float sc = bv[0];
#pragma unroll
        for (int w = 0; w < 8; ++w) sc += ssum[w][tid];
        score[b * SS + s0 + tid] = sc;
    }
}

// ---------------- K3a: softmax over S per batch ----------------
__global__ void softmax_kernel(const float* __restrict__ score, float* __restrict__ weights) {
    __shared__ float red[8];
    const int b = blockIdx.x;
    const int t = threadIdx.x;  // 256
    float local[8];
    float mx = -1e30f;
#pragma unroll
    for (int i = 0; i < 8; ++i) {
        local[i] = score[b * SS + i * 256 + t];
        mx = fmaxf(mx, local[i]);
    }
    for (int off = 1; off < 64; off <<= 1) mx = fmaxf(mx, __shfl_xor(mx, off));
    if ((t & 63) == 0) red[t >> 6] = mx;
    __syncthreads();
    const float m = fmaxf(fmaxf(red[0], red[1]), fmaxf(red[2], red[3]));
    float sum = 0.f;
#pragma unroll
    for (int i = 0; i < 8; ++i) {
        local[i] = __expf(local[i] - m);
        sum += local[i];
    }
    for (int off = 1; off < 64; off <<= 1) sum += __shfl_xor(sum, off);
    if ((t & 63) == 0) red[4 + (t >> 6)] = sum;
    __syncthreads();
    const float inv = 1.f / (red[4] + red[5] + red[6] + red[7]);
#pragma unroll
    for (int i = 0; i < 8; ++i) weights[b * SS + i * 256 + t] = local[i] * inv;
}

// ---------------- K3b: context[b,d] = sum_s w[b,s] * values[b,s,d] ----------------
__global__ void context_kernel(const float* __restrict__ values, const float* __restrict__ weights,
                               float* __restrict__ ctx) {
    __shared__ float ws[SS];          // 8 KB
    __shared__ f32x4 red[16][16];     // 4 KB
    const int b = blockIdx.x;   // 32
    const int dc = blockIdx.y;  // 16
    const int t = threadIdx.x;  // 256
    for (int i = t; i < SS; i += 256) ws[i] = weights[b * SS + i];
    __syncthreads();
    const int dt = t & 15;      // 16 d-threads (64 cols)
    const int ph = t >> 4;      // 16 s-phases
    const int d = dc * 64 + dt * 4;
    const float* vb = values + (size_t)b * SS * DD + d;
    f32x4 acc = {0.f, 0.f, 0.f, 0.f};
#pragma unroll 8
    for (int s = ph; s < SS; s += 16) {
        const float w = ws[s];
        f32x4 v = ntload4(vb + (size_t)s * DD);
        acc[0] = fmaf(w, v[0], acc[0]);
        acc[1] = fmaf(w, v[1], acc[1]);
        acc[2] = fmaf(w, v[2], acc[2]);
        acc[3] = fmaf(w, v[3], acc[3]);
    }
    red[ph][dt] = acc;
    __syncthreads();
    if (t < 16) {
        f32x4 r = red[0][t];
#pragma unroll
        for (int w = 1; w < 16; ++w) {
            f32x4 x = red[w][t];
#pragma unroll
            for (int i = 0; i < 4; ++i) r[i] += x[i];
        }
        *reinterpret_cast<f32x4*>(ctx + (size_t)b * DD + dc * 64 + t * 4) = r;
    }
}

extern "C" void kernel_launch(void* const* d_in, const int* in_sizes, int n_in,
                              void* d_out, int out_size, void* d_ws, size_t ws_size,
                              hipStream_t stream) {
    const float* query  = (const float*)d_in[0];
    const float* values = (const float*)d_in[1];
    const float* w1     = (const float*)d_in[2];
    const float* b1     = (const float*)d_in[3];
    const float* w2     = (const float*)d_in[4];
    const float* b2     = (const float*)d_in[5];
    const float* wv     = (const float*)d_in[6];
    const float* bv     = (const float*)d_in[7];

    float* ctx     = (float*)d_out;                    // [B, D]
    float* weights = (float*)d_out + (size_t)BB * DD;  // [B, S, 1]

    float* qp2           = (float*)d_ws;                                  // 128 KB
    unsigned short* w2p  = (unsigned short*)((char*)d_ws + 131072);       // 2 MB
    float* score         = (float*)((char*)d_ws + 131072 + 2097152);      // 256 KB

    qproj_kernel<<<dim3(BB, UU / 256), 256, 0, stream>>>(query, w1, b1, b2, qp2);
    w2p_kernel<<<dim3(512), 256, 0, stream>>>(w2, w2p);
    score_kernel<<<dim3(BB * SS / MBLK), 512, 0, stream>>>(values, w2p, qp2, wv, bv, score);
    softmax_kernel<<<dim3(BB), 256, 0, stream>>>(score, weights);
    context_kernel<<<dim3(BB, 16), 256, 0, stream>>>(values, weights, ctx);
}